// Round 24
// baseline (722.219 us; speedup 1.0000x reference)
//
#include <hip/hip_runtime.h>
#include <math.h>

#define NN 8192
#define NE 131072
#define NKT 125
#define NT  126      // 125 spline tiles + 1 root tile
#define NRB 128      // row blocks of 64 rows
#define NB2 (NRB*NT*4)          // pair buckets (x4 row-quadrants)
#define NSL 16       // tile-slices for fused conv (8 tiles per slice)
#define K2  256      // final GEMM K (plain f16 operands)
#define PAIRCAP 3100000         // >= NE*8+NN + 31*NB2 (32-padded buckets)

typedef __attribute__((ext_vector_type(8))) short short8v;
typedef _Float16 f16x8 __attribute__((ext_vector_type(8)));
typedef __attribute__((ext_vector_type(4))) float f32x4;

__device__ inline unsigned short bf16rne(float v){
  unsigned u = __float_as_uint(v);
  u += 0x7FFF + ((u>>16)&1);
  return (unsigned short)(u>>16);
}

__device__ inline unsigned short f16b(float v){
  _Float16 h = (_Float16)v;
  unsigned short u; __builtin_memcpy(&u,&h,2); return u;
}

__device__ inline float f16f(unsigned short u){
  _Float16 h; __builtin_memcpy(&h,&u,2); return (float)h;
}

__device__ inline void lds_fadd(float* p, float v){
  unsafeAtomicAdd(p, v);   // native ds_add_f32 (layer-1 builder)
}

__device__ inline void gload16(const void* g, void* l){
  __builtin_amdgcn_global_load_lds((const __attribute__((address_space(1))) void*)g,
                                   (__attribute__((address_space(3))) void*)l, 16, 0, 0);
}

// ---------------- basis + dst histogram (fused) ----------------
__global__ void k_basis(const float* __restrict__ pseudo, const int* __restrict__ dst,
                        unsigned* __restrict__ bpk, int* __restrict__ kidx,
                        int* __restrict__ cnt) {
  int e = blockIdx.x * 256 + threadIdx.x;
  if (e >= NE) return;
  float s0 = pseudo[e*3+0]*4.f, s1 = pseudo[e*3+1]*4.f, s2 = pseudo[e*3+2]*4.f;
  float f0 = floorf(s0), f1 = floorf(s1), f2 = floorf(s2);
  int l0=(int)f0, l1=(int)f1, l2=(int)f2;
  float r0=s0-f0, r1=s1-f1, r2=s2-f2;
  int d = dst[e];
  int kb = (d>>6)*NT;
  int wq = (d>>4)&3;
  #pragma unroll
  for (int s=0;s<8;s++){
    int b0=s&1, b1=(s>>1)&1, b2=(s>>2)&1;
    int i0=min(max(l0+b0,0),4);
    int i1=min(max(l1+b1,0),4);
    int i2=min(max(l2+b2,0),4);
    float w=(b0? r0:1.f-r0)*(b1? r1:1.f-r1)*(b2? r2:1.f-r2);
    int k = i0+5*i1+25*i2;
    bpk[e*8+s]=(unsigned)f16b(w);
    kidx[e*8+s]=k;
    atomicAdd(&cnt[((kb + k)<<2) + wq], 1);
  }
}

// scan over NB2=64512 buckets, 32-multiple rounding; self buckets get +16
__global__ void k_pscan(const int* __restrict__ cnt, int* __restrict__ offs,
                        int* __restrict__ cur){
  __shared__ int lds[1024];
  int t=threadIdx.x, base=t*63;
  int s=0;
  for (int j=0;j<63;j++){
    int b = base+j;
    int c = cnt[b] + ((((b>>2) % NT) == NKT) ? 16 : 0);
    s += (c+31)&~31;
  }
  lds[t]=s; __syncthreads();
  for (int o=1;o<1024;o<<=1){
    int v=(t>=o)?lds[t-o]:0;
    __syncthreads();
    lds[t]+=v;
    __syncthreads();
  }
  int run=(t==0)?0:lds[t-1];
  for (int j=0;j<63;j++){
    int b = base+j;
    int c = cnt[b] + ((((b>>2) % NT) == NKT) ? 16 : 0);
    offs[b]=run; cur[b]=run;
    run += (c+31)&~31;
  }
  if (t==1023) offs[NB2]=run;
}

// pair word: src(13) | row(6)<<13 | cell(7)<<19 ; y = f16 basis (low 16)
__global__ void k_pplace(const int* __restrict__ src, const int* __restrict__ dst,
                         const unsigned* __restrict__ bpk, const int* __restrict__ kidx,
                         int* __restrict__ cur, uint2* __restrict__ pairs){
  int e = blockIdx.x*256 + threadIdx.x;
  if (e>=NE) return;
  int d = dst[e];
  unsigned base = (unsigned)src[e] | ((unsigned)(d&63)<<13);
  int kb = (d>>6)*NT;
  int wq = (d>>4)&3;
  #pragma unroll
  for (int c=0;c<8;c++){
    int k = kidx[e*8+c];
    int p = atomicAdd(&cur[((kb + k)<<2) + wq], 1);
    pairs[p] = make_uint2(base | ((unsigned)k<<19), bpk[e*8+c]);
  }
}

__global__ void k_spplace(const int* __restrict__ offs, uint2* __restrict__ pairs){
  int n = blockIdx.x*256 + threadIdx.x;
  if (n>=NN) return;
  int selfb = (((n>>6)*NT + NKT)<<2) + ((n>>4)&3);
  int p = offs[selfb] + (n&15);
  unsigned a = (unsigned)n | ((unsigned)(n&63)<<13) | ((unsigned)NKT<<19);
  pairs[p] = make_uint2(a, 0x00003C00u);   // f16 1.0
}

// ---------------- layer-1 M build: x == 1, lane-parallel over pairs ----------
__global__ void k_fbuild1(const uint2* __restrict__ pairs, const int* __restrict__ poff,
                          float* __restrict__ M1){
  __shared__ float acc[64*128];
  int rb = blockIdx.x, t = threadIdx.x;
  for (int i=t;i<64*128;i+=256) acc[i]=0.f;
  __syncthreads();
  int r0 = poff[(rb*NT)<<2], r1 = poff[(rb*NT + NKT)<<2];  // spline buckets (pads are zero)
  #pragma unroll 4
  for (int j=r0+t; j<r1; j+=256){
    uint2 p = pairs[j];
    int row  = (p.x>>13)&63;
    int cell = (p.x>>19)&127;
    lds_fadd(&acc[row*128 + cell], f16f((unsigned short)(p.y & 0xFFFFu)));
  }
  __syncthreads();
  size_t base = (size_t)rb*64*128;
  for (int i=t;i<64*128;i+=256) M1[base+i] = acc[i];
}

// ---------------- W prep (W + root in one launch): -> transposed f16 [64][PS] --
template<int CIN>
__global__ void k_wprep(const float* __restrict__ W, const float* __restrict__ R,
                        unsigned short* __restrict__ Wh){
  constexpr int PS = CIN + 8;
  int kb = blockIdx.x; int t = threadIdx.x;     // kb in [0,NT)
  const float* Wk = (kb < NKT) ? (W + (size_t)kb*CIN*64) : R;
  unsigned short* Hk = Wh + (size_t)kb*64*PS;
  for (int idx=t; idx<CIN*64; idx+=256){
    int o = idx/CIN, i = idx - o*CIN;
    Hk[o*PS+i] = f16b(Wk[i*64 + o]);
  }
}

// ---------------- L2w prep: [256][8192] fp32 -> transposed f16 [8192][256] -----
__global__ void k_bprep(const float* __restrict__ B, unsigned short* __restrict__ B2){
  __shared__ float tile[32][132];
  int kb = blockIdx.x & 7;
  int cbk = blockIdx.x >> 3;
  int t = threadIdx.x;
  int k0 = kb*32, c0 = cbk*128;
  #pragma unroll
  for (int q=0;q<4;q++){
    int lin = t + 256*q;
    int r = lin>>5;
    int c4 = (lin&31)*4;
    float4 v = *(const float4*)&B[(size_t)(k0+r)*8192 + c0 + c4];
    tile[r][c4]=v.x; tile[r][c4+1]=v.y; tile[r][c4+2]=v.z; tile[r][c4+3]=v.w;
  }
  __syncthreads();
  int col = t>>1, half = t&1;
  size_t ob = (size_t)(c0+col)*K2 + k0 + half*16;
  #pragma unroll
  for (int i=0;i<16;i++)
    B2[ob+i] = f16b(tile[half*16+i][col]);
}

// ---------------- fused conv: f16-single arithmetic, NSL=16 --------------------
template<int TK>   // TK == CIN in {32,64}
__global__ __launch_bounds__(256, 5) void k_mconv(const unsigned short* __restrict__ xpk,
    const unsigned short* __restrict__ Wh,
    const uint2* __restrict__ pairs, const int* __restrict__ poff,
    float* __restrict__ Cp) {
  constexpr int KK = TK/32;
  constexpr int NCB = TK/16;
  constexpr int STR = TK + 4;
  constexpr int PS = TK + 8;
  constexpr int TPS = NT/NSL + 1;      // 8 tiles per slice
  __shared__ float Msh[4][16*STR];
  __shared__ alignas(16) unsigned short WshH[64*PS];
  int t=threadIdx.x, w=t>>6, lane=t&63;
  int lr=lane&15, kq=lane>>4;
  int rb=blockIdx.x, s=blockIdx.y;
  int t0=s*TPS, t1=min(NT, t0+TPS);

  f32x4 acc[4];
  #pragma unroll
  for (int j=0;j<4;j++) acc[j]=(f32x4){0.f,0.f,0.f,0.f};

  float* ms = &Msh[w][0];

  for (int tile=t0; tile<t1; ++tile){
    // ---- stage W tile into LDS (linear dest, cooperative) ----
    {
      const unsigned short* wh = Wh + (size_t)tile*64*PS;
      for (int idx=t*8; idx<64*PS; idx+=256*8)
        gload16(wh + idx, &WshH[idx]);
    }
    int bkey = ((rb*NT + tile)<<2) + w;
    int r0 = poff[bkey], r1 = poff[bkey+1];
    __syncthreads();                       // W visible (vmcnt drained)
    if (r0 != r1){
      // ---- scatter: M quadrant = S^T·X over this wave's pairs ----
      f32x4 am[NCB];
      #pragma unroll
      for (int cb=0;cb<NCB;cb++) am[cb]=(f32x4){0.f,0.f,0.f,0.f};
      int nch = (r1 - r0) >> 5;            // buckets are 32-padded (pads: basis 0)
      for (int ci=0; ci<nch; ++ci){
        const uint2* pp = pairs + r0 + ci*32;
        uint2 mj[8];
        #pragma unroll
        for (int j=0;j<8;j++) mj[j] = pp[kq*8 + j];
        unsigned short xs[8][NCB];
        #pragma unroll
        for (int j=0;j<8;j++){
          unsigned base = (mj[j].x & 0x1FFF)*TK;
          if constexpr (TK==64){
            uint2 v = *(const uint2*)&xpk[base + lr*4];
            xs[j][0]=(unsigned short)(v.x&0xFFFFu); xs[j][1]=(unsigned short)(v.x>>16);
            xs[j][2]=(unsigned short)(v.y&0xFFFFu); xs[j][3]=(unsigned short)(v.y>>16);
          } else {
            unsigned v = *(const unsigned*)&xpk[base + lr*2];
            xs[j][0]=(unsigned short)(v&0xFFFFu); xs[j][1]=(unsigned short)(v>>16);
          }
        }
        short8v Ai;
        #pragma unroll
        for (int j=0;j<8;j++){
          bool eq = (((mj[j].x>>13)&15) == lr);   // quadrant pre-sorted == w
          Ai[j] = eq ? (short)(mj[j].y & 0xFFFFu) : (short)0;
        }
        f16x8 Af = __builtin_bit_cast(f16x8, Ai);
        #pragma unroll
        for (int cb=0; cb<NCB; ++cb){
          short8v Xi;
          #pragma unroll
          for (int j=0;j<8;j++) Xi[j] = (short)xs[j][cb];
          f16x8 Xf = __builtin_bit_cast(f16x8, Xi);
          am[cb]=__builtin_amdgcn_mfma_f32_16x16x32_f16(Af,Xf,am[cb],0,0,0);
        }
      }
      // ---- transpose via wave-private quadrant (no barrier) ----
      #pragma unroll
      for (int cb=0;cb<NCB;cb++)
        #pragma unroll
        for (int r=0;r<4;r++)
          ms[(kq*4 + r)*STR + cb*16 + lr] = am[cb][r];
      // ---- M·W with f16 W fragments from LDS ----
      #pragma unroll
      for (int kk=0;kk<KK;kk++){
        int e0 = lr*STR + kk*32 + kq*8;
        f32x4 a0 = *(const f32x4*)&ms[e0];
        f32x4 a1 = *(const f32x4*)&ms[e0+4];
        f16x8 ah;
        #pragma unroll
        for (int u=0;u<4;u++){ ah[u]=(_Float16)a0[u]; ah[u+4]=(_Float16)a1[u]; }
        #pragma unroll
        for (int fn=0;fn<4;fn++){
          int off=(fn*16+lr)*PS + kk*32 + kq*8;
          f16x8 wh = *(const f16x8*)&WshH[off];
          acc[fn]=__builtin_amdgcn_mfma_f32_16x16x32_f16(ah,wh,acc[fn],0,0,0);
        }
      }
    }
    __syncthreads();                       // all reads of Wsh done before restage
  }

  size_t sbase = (size_t)s*NN*64;
  #pragma unroll
  for (int fn=0;fn<4;fn++)
    #pragma unroll
    for (int r=0;r<4;r++){
      int row = rb*64 + w*16 + kq*4 + r;
      Cp[sbase + (size_t)row*64 + fn*16 + lr] = acc[fn][r];
    }
}

// ---------------- conv GEMM (layer 1 only), split-bf16 MFMA ----------------
template<int BN>
__global__ __launch_bounds__(256) void k_gconv(const float* __restrict__ A,
                                               const float* __restrict__ B,
                                               float* __restrict__ Cp,
                                               int K, int lda, int nsl) {
  __shared__ alignas(16) char smem[2*128*128 + 2*BN*128];
  char* Ahp = smem;
  char* Alp = smem + 128*128;
  char* Bhp = smem + 2*128*128;
  char* Blp = Bhp + BN*128;

  int t = threadIdx.x;
  int w = t>>6, lane = t&63;
  int lr = lane & 15, kq = lane >> 4;
  int rb = blockIdx.x*128;
  int sl = blockIdx.y;
  int len = ((K + nsl - 1)/nsl + 63) & ~63;
  int kbeg = sl*len;
  int kend = min(K, kbeg + len);

  f32x4 acc[2][BN/16];
  #pragma unroll
  for (int i=0;i<2;i++)
    #pragma unroll
    for (int j=0;j<BN/16;j++) acc[i][j] = (f32x4){0.f,0.f,0.f,0.f};

  for (int k0 = kbeg; k0 < kend; k0 += 64) {
    #pragma unroll
    for (int q=0;q<8;q++){
      int lin = t + 256*q;
      int row = lin >> 4;
      int f4  = lin & 15;
      int kg = k0 + f4*4;
      const float* ap = A + (size_t)(rb+row)*lda + kg;
      float4 v; v.x=0.f; v.y=0.f; v.z=0.f; v.w=0.f;
      if (kg + 3 < kend) v = *(const float4*)ap;
      else {
        if (kg   < kend) v.x = ap[0];
        if (kg+1 < kend) v.y = ap[1];
        if (kg+2 < kend) v.z = ap[2];
      }
      unsigned short h[4], l[4];
      float vv[4] = {v.x, v.y, v.z, v.w};
      #pragma unroll
      for (int u=0;u<4;u++){
        unsigned short hh = bf16rne(vv[u]);
        float fh = __uint_as_float(((unsigned)hh)<<16);
        h[u]=hh; l[u]=bf16rne(vv[u]-fh);
      }
      int bo = (row*128 + f4*8) ^ ((row&7)<<4);
      *(uint2*)(Ahp + bo) = make_uint2((unsigned)h[0]|((unsigned)h[1]<<16),
                                       (unsigned)h[2]|((unsigned)h[3]<<16));
      *(uint2*)(Alp + bo) = make_uint2((unsigned)l[0]|((unsigned)l[1]<<16),
                                       (unsigned)l[2]|((unsigned)l[3]<<16));
    }
    constexpr int BITER = (64*(BN/4))/256;
    #pragma unroll
    for (int q=0;q<BITER;q++){
      int lin = t + 256*q;
      int kr = lin / (BN/4);
      int c4 = (lin % (BN/4))*4;
      int kg = k0 + kr;
      float4 v; v.x=0.f; v.y=0.f; v.z=0.f; v.w=0.f;
      if (kg < kend) v = *(const float4*)&B[(size_t)kg*BN + c4];
      float vv[4] = {v.x, v.y, v.z, v.w};
      #pragma unroll
      for (int u=0;u<4;u++){
        int n = c4 + u;
        unsigned short hh = bf16rne(vv[u]);
        float fh = __uint_as_float(((unsigned)hh)<<16);
        int bo = (n*128 + kr*2) ^ ((n&7)<<4);
        *(unsigned short*)(Bhp + bo) = hh;
        *(unsigned short*)(Blp + bo) = bf16rne(vv[u]-fh);
      }
    }
    __syncthreads();
    int wrow = w*32;
    #pragma unroll
    for (int kk=0;kk<2;kk++){
      int kbyte = (kk*32 + kq*8)*2;
      short8v ah[2], al[2];
      #pragma unroll
      for (int fm=0;fm<2;fm++){
        int row = wrow + fm*16 + lr;
        int bo = (row*128 + kbyte) ^ ((row&7)<<4);
        ah[fm] = *(const short8v*)(Ahp + bo);
        al[fm] = *(const short8v*)(Alp + bo);
      }
      #pragma unroll
      for (int fn=0;fn<BN/16;fn++){
        int n = fn*16 + lr;
        int bo = (n*128 + kbyte) ^ ((n&7)<<4);
        short8v bh = *(const short8v*)(Bhp + bo);
        short8v bl = *(const short8v*)(Blp + bo);
        #pragma unroll
        for (int fm=0;fm<2;fm++){
          acc[fm][fn] = __builtin_amdgcn_mfma_f32_16x16x32_bf16(ah[fm], bh, acc[fm][fn], 0,0,0);
          acc[fm][fn] = __builtin_amdgcn_mfma_f32_16x16x32_bf16(ah[fm], bl, acc[fm][fn], 0,0,0);
          acc[fm][fn] = __builtin_amdgcn_mfma_f32_16x16x32_bf16(al[fm], bh, acc[fm][fn], 0,0,0);
        }
      }
    }
    __syncthreads();
  }
  size_t sbase = (size_t)sl * NN * BN;
  int r0g = rb + w*32;
  #pragma unroll
  for (int fm=0;fm<2;fm++)
    #pragma unroll
    for (int fn=0;fn<BN/16;fn++)
      #pragma unroll
      for (int r=0;r<4;r++){
        int row = r0g + fm*16 + kq*4 + r;
        int col = fn*16 + lr;
        Cp[sbase + (size_t)row*BN + col] = acc[fm][fn][r];
      }
}

// ---------------- layer-1 reduce: partials + (R1+B1), ELU -> permuted f16 ------
__global__ void k_reduce1(const float* __restrict__ Cp, const float* __restrict__ R1,
                          const float* __restrict__ B1, unsigned short* __restrict__ Hpk) {
  int i = blockIdx.x*256 + threadIdx.x;   // over NN*32
  int c = i & 31;
  float v = R1[c] + B1[c];
  #pragma unroll
  for (int s=0;s<8;s++) v += Cp[(size_t)s*NN*32 + i];
  v = v>0.f ? v : expm1f(v);
  int pos = (c&15)*2 + (c>>4);            // channel-permuted for wide gathers
  Hpk[(i & ~31) + pos] = f16b(v);
}

// ---------------- fused-layer reduce: partials + bias, ELU -> permuted + fp32 --
__global__ void k_reduce2(const float* __restrict__ Cp, const float* __restrict__ B,
                          unsigned short* __restrict__ Hpk, float* __restrict__ Hf) {
  int i = blockIdx.x*256 + threadIdx.x;   // over NN*64
  int c = i & 63;
  float v = B[c];
  #pragma unroll
  for (int s=0;s<NSL;s++) v += Cp[(size_t)s*NN*64 + i];
  v = v>0.f ? v : expm1f(v);
  int pos = (c&15)*4 + (c>>4);            // channel-permuted for wide gathers
  Hpk[(i & ~63) + pos] = f16b(v);
  Hf[i] = v;
}

// ---------------- Linear(64,256) + ELU -> plain f16 row ----------------
__global__ void k_l1(const float* __restrict__ H, const float* __restrict__ Wm,
                     const float* __restrict__ b, unsigned short* __restrict__ A2) {
  int n = blockIdx.x, o = threadIdx.x;
  float s = b[o];
  #pragma unroll 16
  for (int i=0;i<64;i++) s += H[(size_t)n*64+i]*Wm[i*256+o];
  s = s>0.f ? s : expm1f(s);
  A2[(size_t)n*K2 + o] = f16b(s);
}

// ---------------- Linear(256,8192): f16 GEMM, 128x256 tile, logits f16 ---------
__global__ __launch_bounds__(256) void k_l2g(
    const unsigned short* __restrict__ A2, const unsigned short* __restrict__ B2,
    const float* __restrict__ bias, unsigned short* __restrict__ C16,
    float* __restrict__ pstats) {
  __shared__ alignas(16) unsigned short As[128*64];
  __shared__ alignas(16) unsigned short Bs[256*64];
  int t = threadIdx.x, w = t>>6, lane = t&63;
  int lr = lane&15, kq = lane>>4;
  int rb = blockIdx.y*128, cb = blockIdx.x*256;
  int wcol = w*64;

  f32x4 acc[8][4];
  #pragma unroll
  for (int i=0;i<8;i++)
    #pragma unroll
    for (int j=0;j<4;j++) acc[i][j] = (f32x4){0.f,0.f,0.f,0.f};

  for (int k0=0; k0<K2; k0+=64) {
    // stage A (16KB): 4 gload16/thread
    #pragma unroll
    for (int q=0;q<4;q++){
      unsigned lo = (unsigned)w*4096 + (unsigned)q*1024 + (unsigned)lane*16;
      int row = lo>>7;
      int kb  = (int)(lo&127) ^ ((row&7)<<4);
      gload16(A2 + (size_t)(rb+row)*K2 + k0 + (kb>>1), (unsigned short*)As + (lo>>1));
    }
    // stage B (32KB): 8 gload16/thread
    #pragma unroll
    for (int q=0;q<8;q++){
      unsigned lo = (unsigned)w*8192 + (unsigned)q*1024 + (unsigned)lane*16;
      int row = lo>>7;
      int kb  = (int)(lo&127) ^ ((row&7)<<4);
      gload16(B2 + (size_t)(cb+row)*K2 + k0 + (kb>>1), (unsigned short*)Bs + (lo>>1));
    }
    __syncthreads();
    #pragma unroll
    for (int kk=0;kk<2;kk++){
      f16x8 af[8], bf[4];
      #pragma unroll
      for (int fm=0;fm<8;fm++){
        int row = fm*16 + lr;
        int bo = (row*128 + kk*64 + kq*16) ^ ((row&7)<<4);
        af[fm] = *(const f16x8*)((const char*)As + bo);
      }
      #pragma unroll
      for (int fn=0;fn<4;fn++){
        int col = wcol + fn*16 + lr;
        int bo = (col*128 + kk*64 + kq*16) ^ ((col&7)<<4);
        bf[fn] = *(const f16x8*)((const char*)Bs + bo);
      }
      #pragma unroll
      for (int fn=0;fn<4;fn++)
        #pragma unroll
        for (int fm=0;fm<8;fm++)
          acc[fm][fn] = __builtin_amdgcn_mfma_f32_16x16x32_f16(af[fm], bf[fn], acc[fm][fn], 0,0,0);
    }
    __syncthreads();
  }

  float bcol[4];
  #pragma unroll
  for (int fn=0;fn<4;fn++) bcol[fn] = bias[cb + wcol + fn*16 + lr];
  int cchunk = blockIdx.x*4 + w;
  #pragma unroll
  for (int fm=0;fm<8;fm++){
    #pragma unroll
    for (int r=0;r<4;r++){
      int rowg = rb + fm*16 + kq*4 + r;
      float v0 = acc[fm][0][r] + bcol[0];
      float v1 = acc[fm][1][r] + bcol[1];
      float v2 = acc[fm][2][r] + bcol[2];
      float v3 = acc[fm][3][r] + bcol[3];
      size_t obase = (size_t)rowg*8192 + cb + wcol + lr;
      C16[obase]      = f16b(v0);
      C16[obase+16]   = f16b(v1);
      C16[obase+32]   = f16b(v2);
      C16[obase+48]   = f16b(v3);
      float m = fmaxf(fmaxf(v0,v1),fmaxf(v2,v3));
      #pragma unroll
      for (int mk=1;mk<16;mk<<=1) m = fmaxf(m, __shfl_xor(m, mk, 64));
      float s = __expf(v0-m)+__expf(v1-m)+__expf(v2-m)+__expf(v3-m);
      #pragma unroll
      for (int mk=1;mk<16;mk<<=1) s += __shfl_xor(s, mk, 64);
      if (lr==0){
        size_t pb = ((size_t)rowg*128 + cchunk)*2;   // [row][chunk] layout
        pstats[pb]   = m;
        pstats[pb+1] = s;
      }
    }
  }
}

// ---------------- per-row logsumexp: one wave per row, shfl merge --------------
__global__ void k_lsmfin(const float* __restrict__ ps, float* __restrict__ lg) {
  int gw = (blockIdx.x*256 + threadIdx.x)>>6;   // row
  int lane = threadIdx.x & 63;
  const float4 v = *(const float4*)&ps[(size_t)gw*256 + lane*4];  // {m0,s0,m1,s1}
  float M = fmaxf(v.x, v.z);
  float S = __expf(v.x-M)*v.y + __expf(v.z-M)*v.w;
  #pragma unroll
  for (int o=1;o<64;o<<=1){
    float M2 = __shfl_xor(M,o,64), S2 = __shfl_xor(S,o,64);
    float Mn = fmaxf(M,M2);
    S = S*__expf(M-Mn) + S2*__expf(M2-Mn);
    M = Mn;
  }
  if (lane==0) lg[gw] = M + logf(S);
}

// ---------------- final: out = (float)logit_f16 - lg[row] ----------------------
__global__ void k_lsub(const unsigned short* __restrict__ C16,
                       const float* __restrict__ lg, float* __restrict__ O) {
  int i = blockIdx.x*256 + threadIdx.x;   // over NN*8192/8 groups
  short8v v = ((const short8v*)C16)[i];
  f16x8 h = __builtin_bit_cast(f16x8, v);
  float L = lg[i>>10];                     // 1024 groups of 8 per row
  float4 o0, o1;
  o0.x=(float)h[0]-L; o0.y=(float)h[1]-L; o0.z=(float)h[2]-L; o0.w=(float)h[3]-L;
  o1.x=(float)h[4]-L; o1.y=(float)h[5]-L; o1.z=(float)h[6]-L; o1.w=(float)h[7]-L;
  ((float4*)O)[i*2]   = o0;
  ((float4*)O)[i*2+1] = o1;
}

extern "C" void kernel_launch(void* const* d_in, const int* in_sizes, int n_in,
                              void* d_out, int out_size, void* d_ws, size_t ws_size,
                              hipStream_t stream) {
  (void)in_sizes; (void)n_in; (void)out_size; (void)ws_size;
  const float* x0     = (const float*)d_in[0]; (void)x0;
  const int*   ei     = (const int*)d_in[1];
  const float* pseudo = (const float*)d_in[2];
  const float* W[6]; const float* R[6]; const float* Bb[6];
  for (int l=0;l<6;l++){
    W[l]=(const float*)d_in[3+3*l];
    R[l]=(const float*)d_in[4+3*l];
    Bb[l]=(const float*)d_in[5+3*l];
  }
  const float* L1w=(const float*)d_in[21];
  const float* L1b=(const float*)d_in[22];
  const float* L2w=(const float*)d_in[23];
  const float* L2b=(const float*)d_in[24];
  float* out = (float*)d_out;
  char* ws = (char*)d_ws;

  size_t off=0;
  auto alloc=[&](size_t bytes)->void*{
    size_t o=off; off += (bytes+511)&~511ULL; return (void*)(ws+o);
  };
  unsigned* bpk =(unsigned*)alloc((size_t)NE*8*4);
  int*   kidx  =(int*)  alloc((size_t)NE*8*4);
  int*   pcnt  =(int*)  alloc((size_t)NB2*4);
  int*   poff  =(int*)  alloc((size_t)(NB2+1)*4);
  int*   pcur  =(int*)  alloc((size_t)(NB2+1)*4);
  uint2* pairs =(uint2*)alloc((size_t)PAIRCAP*8);
  float* M1    =(float*)alloc((size_t)NN*128*4);
  unsigned short* Wh=(unsigned short*)alloc((size_t)NT*64*72*2);
  unsigned short* xpk32=(unsigned short*)alloc((size_t)NN*32*2);
  unsigned short* hpkA =(unsigned short*)alloc((size_t)NN*64*2);
  unsigned short* hpkB =(unsigned short*)alloc((size_t)NN*64*2);
  float* hf    =(float*)alloc((size_t)NN*64*4);
  unsigned short* A2=(unsigned short*)alloc((size_t)NN*K2*2);
  unsigned short* B2=(unsigned short*)alloc((size_t)NN*K2*2);
  unsigned short* C16=(unsigned short*)alloc((size_t)NN*NN*2);
  float* pstats=(float*)alloc((size_t)NN*128*2*4);
  float* lg    =(float*)alloc((size_t)NN*4);
  float* cpart = out;   // d_out (256 MB) doubles as split-K partial scratch

  const int* src = ei;
  const int* dst = ei + NE;

  hipMemsetAsync(pcnt, 0, (size_t)NB2*4, stream);
  hipMemsetAsync(pairs, 0, (size_t)PAIRCAP*8, stream);   // zero-pad buckets
  k_basis<<<NE/256,256,0,stream>>>(pseudo,dst,bpk,kidx,pcnt);
  k_pscan<<<1,1024,0,stream>>>(pcnt,poff,pcur);
  k_pplace<<<NE/256,256,0,stream>>>(src,dst,bpk,kidx,pcur,pairs);
  k_spplace<<<NN/256,256,0,stream>>>(poff,pairs);
  k_bprep<<<512,256,0,stream>>>(L2w,B2);

  dim3 gg(64, 8);
  dim3 gf(NRB, NSL);
  // layer 1: 1 -> 32 (x == 1): pair-built M1, GEMM, reduce (permuted f16 out)
  k_fbuild1<<<NRB,256,0,stream>>>(pairs,poff,M1);
  k_gconv<32><<<gg,256,0,stream>>>(M1,W[0],cpart,125,128,8);
  k_reduce1<<<(NN*32)/256,256,0,stream>>>(cpart,R[0],Bb[0],xpk32);
  // layer 2: 32 -> 64
  k_wprep<32><<<NT,256,0,stream>>>(W[1],R[1],Wh);
  k_mconv<32><<<gf,256,0,stream>>>(xpk32,Wh,pairs,poff,cpart);
  k_reduce2<<<(NN*64)/256,256,0,stream>>>(cpart,Bb[1],hpkA,hf);
  // layers 3..6: 64 -> 64
  unsigned short* hin=hpkA; unsigned short* hout=hpkB;
  for (int l=2;l<6;l++){
    k_wprep<64><<<NT,256,0,stream>>>(W[l],R[l],Wh);
    k_mconv<64><<<gf,256,0,stream>>>(hin,Wh,pairs,poff,cpart);
    k_reduce2<<<(NN*64)/256,256,0,stream>>>(cpart,Bb[l],hout,hf);
    unsigned short* tmp=hin; hin=hout; hout=tmp;
  }
  // hf holds layer-6 fp32 output
  k_l1<<<NN,256,0,stream>>>(hf,L1w,L1b,A2);
  dim3 g2(32,64);
  k_l2g<<<g2,256,0,stream>>>(A2,B2,L2b,C16,pstats);
  k_lsmfin<<<NN*64/256,256,0,stream>>>(pstats,lg);
  k_lsub<<<(NN*8192/8)/256,256,0,stream>>>(C16,lg,out);
}

// Round 25
// 655.985 us; speedup vs baseline: 1.1010x; 1.1010x over previous
//
#include <hip/hip_runtime.h>
#include <math.h>

#define NN 8192
#define NE 131072
#define NKT 125
#define NT  126      // 125 spline tiles + 1 root tile
#define NRB 128      // row blocks of 64 rows
#define NB2 (NRB*NT*4)          // pair buckets (x4 row-quadrants)
#define NSL 16       // tile-slices for fused conv (8 tiles per slice)
#define K2  256      // final GEMM K (plain f16 operands)
#define PAIRCAP 3100000         // >= NE*8+NN + 31*NB2 (32-padded buckets)

typedef __attribute__((ext_vector_type(8))) short short8v;
typedef _Float16 f16x8 __attribute__((ext_vector_type(8)));
typedef __attribute__((ext_vector_type(4))) float f32x4;

__device__ inline unsigned short bf16rne(float v){
  unsigned u = __float_as_uint(v);
  u += 0x7FFF + ((u>>16)&1);
  return (unsigned short)(u>>16);
}

__device__ inline unsigned short f16b(float v){
  _Float16 h = (_Float16)v;
  unsigned short u; __builtin_memcpy(&u,&h,2); return u;
}

__device__ inline float f16f(unsigned short u){
  _Float16 h; __builtin_memcpy(&h,&u,2); return (float)h;
}

__device__ inline void lds_fadd(float* p, float v){
  unsafeAtomicAdd(p, v);   // native ds_add_f32 (layer-1 builder)
}

__device__ inline void gload16(const void* g, void* l){
  __builtin_amdgcn_global_load_lds((const __attribute__((address_space(1))) void*)g,
                                   (__attribute__((address_space(3))) void*)l, 16, 0, 0);
}

// ---------------- basis + dst histogram (fused) ----------------
__global__ void k_basis(const float* __restrict__ pseudo, const int* __restrict__ dst,
                        unsigned* __restrict__ bpk, int* __restrict__ kidx,
                        int* __restrict__ cnt) {
  int e = blockIdx.x * 256 + threadIdx.x;
  if (e >= NE) return;
  float s0 = pseudo[e*3+0]*4.f, s1 = pseudo[e*3+1]*4.f, s2 = pseudo[e*3+2]*4.f;
  float f0 = floorf(s0), f1 = floorf(s1), f2 = floorf(s2);
  int l0=(int)f0, l1=(int)f1, l2=(int)f2;
  float r0=s0-f0, r1=s1-f1, r2=s2-f2;
  int d = dst[e];
  int kb = (d>>6)*NT;
  int wq = (d>>4)&3;
  #pragma unroll
  for (int s=0;s<8;s++){
    int b0=s&1, b1=(s>>1)&1, b2=(s>>2)&1;
    int i0=min(max(l0+b0,0),4);
    int i1=min(max(l1+b1,0),4);
    int i2=min(max(l2+b2,0),4);
    float w=(b0? r0:1.f-r0)*(b1? r1:1.f-r1)*(b2? r2:1.f-r2);
    int k = i0+5*i1+25*i2;
    bpk[e*8+s]=(unsigned)f16b(w);
    kidx[e*8+s]=k;
    atomicAdd(&cnt[((kb + k)<<2) + wq], 1);
  }
}

// scan over NB2=64512 buckets, 32-multiple rounding; self buckets get +16
__global__ void k_pscan(const int* __restrict__ cnt, int* __restrict__ offs,
                        int* __restrict__ cur){
  __shared__ int lds[1024];
  int t=threadIdx.x, base=t*63;
  int s=0;
  for (int j=0;j<63;j++){
    int b = base+j;
    int c = cnt[b] + ((((b>>2) % NT) == NKT) ? 16 : 0);
    s += (c+31)&~31;
  }
  lds[t]=s; __syncthreads();
  for (int o=1;o<1024;o<<=1){
    int v=(t>=o)?lds[t-o]:0;
    __syncthreads();
    lds[t]+=v;
    __syncthreads();
  }
  int run=(t==0)?0:lds[t-1];
  for (int j=0;j<63;j++){
    int b = base+j;
    int c = cnt[b] + ((((b>>2) % NT) == NKT) ? 16 : 0);
    offs[b]=run; cur[b]=run;
    run += (c+31)&~31;
  }
  if (t==1023) offs[NB2]=run;
}

// pair word: src(13) | row(6)<<13 | cell(7)<<19 ; y = f16 basis (low 16)
__global__ void k_pplace(const int* __restrict__ src, const int* __restrict__ dst,
                         const unsigned* __restrict__ bpk, const int* __restrict__ kidx,
                         int* __restrict__ cur, uint2* __restrict__ pairs){
  int e = blockIdx.x*256 + threadIdx.x;
  if (e>=NE) return;
  int d = dst[e];
  unsigned base = (unsigned)src[e] | ((unsigned)(d&63)<<13);
  int kb = (d>>6)*NT;
  int wq = (d>>4)&3;
  #pragma unroll
  for (int c=0;c<8;c++){
    int k = kidx[e*8+c];
    int p = atomicAdd(&cur[((kb + k)<<2) + wq], 1);
    pairs[p] = make_uint2(base | ((unsigned)k<<19), bpk[e*8+c]);
  }
}

__global__ void k_spplace(const int* __restrict__ offs, uint2* __restrict__ pairs){
  int n = blockIdx.x*256 + threadIdx.x;
  if (n>=NN) return;
  int selfb = (((n>>6)*NT + NKT)<<2) + ((n>>4)&3);
  int p = offs[selfb] + (n&15);
  unsigned a = (unsigned)n | ((unsigned)(n&63)<<13) | ((unsigned)NKT<<19);
  pairs[p] = make_uint2(a, 0x00003C00u);   // f16 1.0
}

// ---------------- layer-1 M build: x == 1, lane-parallel over pairs ----------
__global__ void k_fbuild1(const uint2* __restrict__ pairs, const int* __restrict__ poff,
                          float* __restrict__ M1){
  __shared__ float acc[64*128];
  int rb = blockIdx.x, t = threadIdx.x;
  for (int i=t;i<64*128;i+=256) acc[i]=0.f;
  __syncthreads();
  int r0 = poff[(rb*NT)<<2], r1 = poff[(rb*NT + NKT)<<2];  // spline buckets (pads are zero)
  #pragma unroll 4
  for (int j=r0+t; j<r1; j+=256){
    uint2 p = pairs[j];
    int row  = (p.x>>13)&63;
    int cell = (p.x>>19)&127;
    lds_fadd(&acc[row*128 + cell], f16f((unsigned short)(p.y & 0xFFFFu)));
  }
  __syncthreads();
  size_t base = (size_t)rb*64*128;
  for (int i=t;i<64*128;i+=256) M1[base+i] = acc[i];
}

// ---------------- W prep (W + root in one launch): -> transposed f16 [64][PS] --
template<int CIN>
__global__ void k_wprep(const float* __restrict__ W, const float* __restrict__ R,
                        unsigned short* __restrict__ Wh){
  constexpr int PS = CIN + 8;
  int kb = blockIdx.x; int t = threadIdx.x;     // kb in [0,NT)
  const float* Wk = (kb < NKT) ? (W + (size_t)kb*CIN*64) : R;
  unsigned short* Hk = Wh + (size_t)kb*64*PS;
  for (int idx=t; idx<CIN*64; idx+=256){
    int o = idx/CIN, i = idx - o*CIN;
    Hk[o*PS+i] = f16b(Wk[i*64 + o]);
  }
}

// ---------------- L2w prep: [256][8192] fp32 -> transposed f16 [8192][256] -----
__global__ void k_bprep(const float* __restrict__ B, unsigned short* __restrict__ B2){
  __shared__ float tile[32][132];
  int kb = blockIdx.x & 7;
  int cbk = blockIdx.x >> 3;
  int t = threadIdx.x;
  int k0 = kb*32, c0 = cbk*128;
  #pragma unroll
  for (int q=0;q<4;q++){
    int lin = t + 256*q;
    int r = lin>>5;
    int c4 = (lin&31)*4;
    float4 v = *(const float4*)&B[(size_t)(k0+r)*8192 + c0 + c4];
    tile[r][c4]=v.x; tile[r][c4+1]=v.y; tile[r][c4+2]=v.z; tile[r][c4+3]=v.w;
  }
  __syncthreads();
  int col = t>>1, half = t&1;
  size_t ob = (size_t)(c0+col)*K2 + k0 + half*16;
  #pragma unroll
  for (int i=0;i<16;i++)
    B2[ob+i] = f16b(tile[half*16+i][col]);
}

// ---------------- fused conv: f16-single arithmetic, NSL=16 --------------------
template<int TK>   // TK == CIN in {32,64}
__global__ __launch_bounds__(256, 5) void k_mconv(const unsigned short* __restrict__ xpk,
    const unsigned short* __restrict__ Wh,
    const uint2* __restrict__ pairs, const int* __restrict__ poff,
    float* __restrict__ Cp) {
  constexpr int KK = TK/32;
  constexpr int NCB = TK/16;
  constexpr int STR = TK + 4;
  constexpr int PS = TK + 8;
  constexpr int TPS = NT/NSL + 1;      // 8 tiles per slice
  __shared__ float Msh[4][16*STR];
  __shared__ alignas(16) unsigned short WshH[64*PS];
  int t=threadIdx.x, w=t>>6, lane=t&63;
  int lr=lane&15, kq=lane>>4;
  int rb=blockIdx.x, s=blockIdx.y;
  int t0=s*TPS, t1=min(NT, t0+TPS);

  f32x4 acc[4];
  #pragma unroll
  for (int j=0;j<4;j++) acc[j]=(f32x4){0.f,0.f,0.f,0.f};

  float* ms = &Msh[w][0];

  for (int tile=t0; tile<t1; ++tile){
    // ---- stage W tile into LDS (linear dest, cooperative) ----
    {
      const unsigned short* wh = Wh + (size_t)tile*64*PS;
      for (int idx=t*8; idx<64*PS; idx+=256*8)
        gload16(wh + idx, &WshH[idx]);
    }
    int bkey = ((rb*NT + tile)<<2) + w;
    int r0 = poff[bkey], r1 = poff[bkey+1];
    __syncthreads();                       // W visible (vmcnt drained)
    if (r0 != r1){
      // ---- scatter: M quadrant = S^T·X over this wave's pairs ----
      f32x4 am[NCB];
      #pragma unroll
      for (int cb=0;cb<NCB;cb++) am[cb]=(f32x4){0.f,0.f,0.f,0.f};
      int nch = (r1 - r0) >> 5;            // buckets are 32-padded (pads: basis 0)
      for (int ci=0; ci<nch; ++ci){
        const uint2* pp = pairs + r0 + ci*32;
        uint2 mj[8];
        #pragma unroll
        for (int j=0;j<8;j++) mj[j] = pp[kq*8 + j];
        unsigned short xs[8][NCB];
        #pragma unroll
        for (int j=0;j<8;j++){
          unsigned base = (mj[j].x & 0x1FFF)*TK;
          if constexpr (TK==64){
            uint2 v = *(const uint2*)&xpk[base + lr*4];
            xs[j][0]=(unsigned short)(v.x&0xFFFFu); xs[j][1]=(unsigned short)(v.x>>16);
            xs[j][2]=(unsigned short)(v.y&0xFFFFu); xs[j][3]=(unsigned short)(v.y>>16);
          } else {
            unsigned v = *(const unsigned*)&xpk[base + lr*2];
            xs[j][0]=(unsigned short)(v&0xFFFFu); xs[j][1]=(unsigned short)(v>>16);
          }
        }
        short8v Ai;
        #pragma unroll
        for (int j=0;j<8;j++){
          bool eq = (((mj[j].x>>13)&15) == lr);   // quadrant pre-sorted == w
          Ai[j] = eq ? (short)(mj[j].y & 0xFFFFu) : (short)0;
        }
        f16x8 Af = __builtin_bit_cast(f16x8, Ai);
        #pragma unroll
        for (int cb=0; cb<NCB; ++cb){
          short8v Xi;
          #pragma unroll
          for (int j=0;j<8;j++) Xi[j] = (short)xs[j][cb];
          f16x8 Xf = __builtin_bit_cast(f16x8, Xi);
          am[cb]=__builtin_amdgcn_mfma_f32_16x16x32_f16(Af,Xf,am[cb],0,0,0);
        }
      }
      // ---- transpose via wave-private quadrant (no barrier) ----
      #pragma unroll
      for (int cb=0;cb<NCB;cb++)
        #pragma unroll
        for (int r=0;r<4;r++)
          ms[(kq*4 + r)*STR + cb*16 + lr] = am[cb][r];
      // ---- M·W with f16 W fragments from LDS ----
      #pragma unroll
      for (int kk=0;kk<KK;kk++){
        int e0 = lr*STR + kk*32 + kq*8;
        f32x4 a0 = *(const f32x4*)&ms[e0];
        f32x4 a1 = *(const f32x4*)&ms[e0+4];
        f16x8 ah;
        #pragma unroll
        for (int u=0;u<4;u++){ ah[u]=(_Float16)a0[u]; ah[u+4]=(_Float16)a1[u]; }
        #pragma unroll
        for (int fn=0;fn<4;fn++){
          int off=(fn*16+lr)*PS + kk*32 + kq*8;
          f16x8 wh = *(const f16x8*)&WshH[off];
          acc[fn]=__builtin_amdgcn_mfma_f32_16x16x32_f16(ah,wh,acc[fn],0,0,0);
        }
      }
    }
    __syncthreads();                       // all reads of Wsh done before restage
  }

  size_t sbase = (size_t)s*NN*64;
  #pragma unroll
  for (int fn=0;fn<4;fn++)
    #pragma unroll
    for (int r=0;r<4;r++){
      int row = rb*64 + w*16 + kq*4 + r;
      Cp[sbase + (size_t)row*64 + fn*16 + lr] = acc[fn][r];
    }
}

// ---------------- conv GEMM (layer 1 only), split-bf16 MFMA ----------------
template<int BN>
__global__ __launch_bounds__(256) void k_gconv(const float* __restrict__ A,
                                               const float* __restrict__ B,
                                               float* __restrict__ Cp,
                                               int K, int lda, int nsl) {
  __shared__ alignas(16) char smem[2*128*128 + 2*BN*128];
  char* Ahp = smem;
  char* Alp = smem + 128*128;
  char* Bhp = smem + 2*128*128;
  char* Blp = Bhp + BN*128;

  int t = threadIdx.x;
  int w = t>>6, lane = t&63;
  int lr = lane & 15, kq = lane >> 4;
  int rb = blockIdx.x*128;
  int sl = blockIdx.y;
  int len = ((K + nsl - 1)/nsl + 63) & ~63;
  int kbeg = sl*len;
  int kend = min(K, kbeg + len);

  f32x4 acc[2][BN/16];
  #pragma unroll
  for (int i=0;i<2;i++)
    #pragma unroll
    for (int j=0;j<BN/16;j++) acc[i][j] = (f32x4){0.f,0.f,0.f,0.f};

  for (int k0 = kbeg; k0 < kend; k0 += 64) {
    #pragma unroll
    for (int q=0;q<8;q++){
      int lin = t + 256*q;
      int row = lin >> 4;
      int f4  = lin & 15;
      int kg = k0 + f4*4;
      const float* ap = A + (size_t)(rb+row)*lda + kg;
      float4 v; v.x=0.f; v.y=0.f; v.z=0.f; v.w=0.f;
      if (kg + 3 < kend) v = *(const float4*)ap;
      else {
        if (kg   < kend) v.x = ap[0];
        if (kg+1 < kend) v.y = ap[1];
        if (kg+2 < kend) v.z = ap[2];
      }
      unsigned short h[4], l[4];
      float vv[4] = {v.x, v.y, v.z, v.w};
      #pragma unroll
      for (int u=0;u<4;u++){
        unsigned short hh = bf16rne(vv[u]);
        float fh = __uint_as_float(((unsigned)hh)<<16);
        h[u]=hh; l[u]=bf16rne(vv[u]-fh);
      }
      int bo = (row*128 + f4*8) ^ ((row&7)<<4);
      *(uint2*)(Ahp + bo) = make_uint2((unsigned)h[0]|((unsigned)h[1]<<16),
                                       (unsigned)h[2]|((unsigned)h[3]<<16));
      *(uint2*)(Alp + bo) = make_uint2((unsigned)l[0]|((unsigned)l[1]<<16),
                                       (unsigned)l[2]|((unsigned)l[3]<<16));
    }
    constexpr int BITER = (64*(BN/4))/256;
    #pragma unroll
    for (int q=0;q<BITER;q++){
      int lin = t + 256*q;
      int kr = lin / (BN/4);
      int c4 = (lin % (BN/4))*4;
      int kg = k0 + kr;
      float4 v; v.x=0.f; v.y=0.f; v.z=0.f; v.w=0.f;
      if (kg < kend) v = *(const float4*)&B[(size_t)kg*BN + c4];
      float vv[4] = {v.x, v.y, v.z, v.w};
      #pragma unroll
      for (int u=0;u<4;u++){
        int n = c4 + u;
        unsigned short hh = bf16rne(vv[u]);
        float fh = __uint_as_float(((unsigned)hh)<<16);
        int bo = (n*128 + kr*2) ^ ((n&7)<<4);
        *(unsigned short*)(Bhp + bo) = hh;
        *(unsigned short*)(Blp + bo) = bf16rne(vv[u]-fh);
      }
    }
    __syncthreads();
    int wrow = w*32;
    #pragma unroll
    for (int kk=0;kk<2;kk++){
      int kbyte = (kk*32 + kq*8)*2;
      short8v ah[2], al[2];
      #pragma unroll
      for (int fm=0;fm<2;fm++){
        int row = wrow + fm*16 + lr;
        int bo = (row*128 + kbyte) ^ ((row&7)<<4);
        ah[fm] = *(const short8v*)(Ahp + bo);
        al[fm] = *(const short8v*)(Alp + bo);
      }
      #pragma unroll
      for (int fn=0;fn<BN/16;fn++){
        int n = fn*16 + lr;
        int bo = (n*128 + kbyte) ^ ((n&7)<<4);
        short8v bh = *(const short8v*)(Bhp + bo);
        short8v bl = *(const short8v*)(Blp + bo);
        #pragma unroll
        for (int fm=0;fm<2;fm++){
          acc[fm][fn] = __builtin_amdgcn_mfma_f32_16x16x32_bf16(ah[fm], bh, acc[fm][fn], 0,0,0);
          acc[fm][fn] = __builtin_amdgcn_mfma_f32_16x16x32_bf16(ah[fm], bl, acc[fm][fn], 0,0,0);
          acc[fm][fn] = __builtin_amdgcn_mfma_f32_16x16x32_bf16(al[fm], bh, acc[fm][fn], 0,0,0);
        }
      }
    }
    __syncthreads();
  }
  size_t sbase = (size_t)sl * NN * BN;
  int r0g = rb + w*32;
  #pragma unroll
  for (int fm=0;fm<2;fm++)
    #pragma unroll
    for (int fn=0;fn<BN/16;fn++)
      #pragma unroll
      for (int r=0;r<4;r++){
        int row = r0g + fm*16 + kq*4 + r;
        int col = fn*16 + lr;
        Cp[sbase + (size_t)row*BN + col] = acc[fm][fn][r];
      }
}

// ---------------- layer-1 reduce: partials + (R1+B1), ELU -> permuted f16 ------
__global__ void k_reduce1(const float* __restrict__ Cp, const float* __restrict__ R1,
                          const float* __restrict__ B1, unsigned short* __restrict__ Hpk) {
  int i = blockIdx.x*256 + threadIdx.x;   // over NN*32
  int c = i & 31;
  float v = R1[c] + B1[c];
  #pragma unroll
  for (int s=0;s<8;s++) v += Cp[(size_t)s*NN*32 + i];
  v = v>0.f ? v : expm1f(v);
  int pos = (c&15)*2 + (c>>4);            // channel-permuted for wide gathers
  Hpk[(i & ~31) + pos] = f16b(v);
}

// ---------------- fused-layer reduce: partials + bias, ELU -> permuted + fp32 --
__global__ void k_reduce2(const float* __restrict__ Cp, const float* __restrict__ B,
                          unsigned short* __restrict__ Hpk, float* __restrict__ Hf) {
  int i = blockIdx.x*256 + threadIdx.x;   // over NN*64
  int c = i & 63;
  float v = B[c];
  #pragma unroll
  for (int s=0;s<NSL;s++) v += Cp[(size_t)s*NN*64 + i];
  v = v>0.f ? v : expm1f(v);
  int pos = (c&15)*4 + (c>>4);            // channel-permuted for wide gathers
  Hpk[(i & ~63) + pos] = f16b(v);
  Hf[i] = v;
}

// ---------------- Linear(64,256) + ELU -> plain f16 row ----------------
__global__ void k_l1(const float* __restrict__ H, const float* __restrict__ Wm,
                     const float* __restrict__ b, unsigned short* __restrict__ A2) {
  int n = blockIdx.x, o = threadIdx.x;
  float s = b[o];
  #pragma unroll 16
  for (int i=0;i<64;i++) s += H[(size_t)n*64+i]*Wm[i*256+o];
  s = s>0.f ? s : expm1f(s);
  A2[(size_t)n*K2 + o] = f16b(s);
}

// ---------------- Linear(256,8192): f16 GEMM, 128x128 tile, logits f16 ---------
__global__ __launch_bounds__(256) void k_l2g(
    const unsigned short* __restrict__ A2, const unsigned short* __restrict__ B2,
    const float* __restrict__ bias, unsigned short* __restrict__ C16,
    float* __restrict__ pstats) {
  __shared__ alignas(16) unsigned short As[128*64];
  __shared__ alignas(16) unsigned short Bs[128*64];
  int t = threadIdx.x, w = t>>6, lane = t&63;
  int lr = lane&15, kq = lane>>4;
  int wr = w>>1, wc = w&1;
  int rb = blockIdx.y*128, cb = blockIdx.x*128;
  int wrow = wr*64, wcol = wc*64;

  unsigned lo0 = (unsigned)(w*4)*1024 + (unsigned)lane*16;
  f32x4 acc[4][4];
  #pragma unroll
  for (int i=0;i<4;i++)
    #pragma unroll
    for (int j=0;j<4;j++) acc[i][j] = (f32x4){0.f,0.f,0.f,0.f};

  for (int k0=0; k0<K2; k0+=64) {
    #pragma unroll
    for (int q=0;q<4;q++){
      unsigned lo = lo0 + (unsigned)q*1024;
      int row = lo>>7;
      int kb  = (int)(lo&127) ^ ((row&7)<<4);       // inverse-swizzled source
      gload16(A2 + (size_t)(rb+row)*K2 + k0 + (kb>>1), (unsigned short*)As + (lo>>1));
      gload16(B2 + (size_t)(cb+row)*K2 + k0 + (kb>>1), (unsigned short*)Bs + (lo>>1));
    }
    __syncthreads();
    #pragma unroll
    for (int kk=0;kk<2;kk++){
      f16x8 af[4], bf[4];
      #pragma unroll
      for (int fm=0;fm<4;fm++){
        int row = wrow + fm*16 + lr;
        int bo = (row*128 + kk*64 + kq*16) ^ ((row&7)<<4);
        af[fm] = *(const f16x8*)((const char*)As + bo);
      }
      #pragma unroll
      for (int fn=0;fn<4;fn++){
        int col = wcol + fn*16 + lr;
        int bo = (col*128 + kk*64 + kq*16) ^ ((col&7)<<4);
        bf[fn] = *(const f16x8*)((const char*)Bs + bo);
      }
      #pragma unroll
      for (int fn=0;fn<4;fn++)
        #pragma unroll
        for (int fm=0;fm<4;fm++)
          acc[fm][fn] = __builtin_amdgcn_mfma_f32_16x16x32_f16(af[fm], bf[fn], acc[fm][fn], 0,0,0);
    }
    __syncthreads();
  }

  float bcol[4];
  #pragma unroll
  for (int fn=0;fn<4;fn++) bcol[fn] = bias[cb + wcol + fn*16 + lr];
  int cchunk = blockIdx.x*2 + wc;
  #pragma unroll
  for (int fm=0;fm<4;fm++){
    #pragma unroll
    for (int r=0;r<4;r++){
      int rowg = rb + wrow + fm*16 + kq*4 + r;
      float v0 = acc[fm][0][r] + bcol[0];
      float v1 = acc[fm][1][r] + bcol[1];
      float v2 = acc[fm][2][r] + bcol[2];
      float v3 = acc[fm][3][r] + bcol[3];
      size_t obase = (size_t)rowg*8192 + cb + wcol + lr;
      C16[obase]      = f16b(v0);
      C16[obase+16]   = f16b(v1);
      C16[obase+32]   = f16b(v2);
      C16[obase+48]   = f16b(v3);
      float m = fmaxf(fmaxf(v0,v1),fmaxf(v2,v3));
      #pragma unroll
      for (int mk=1;mk<16;mk<<=1) m = fmaxf(m, __shfl_xor(m, mk, 64));
      float s = __expf(v0-m)+__expf(v1-m)+__expf(v2-m)+__expf(v3-m);
      #pragma unroll
      for (int mk=1;mk<16;mk<<=1) s += __shfl_xor(s, mk, 64);
      if (lr==0){
        size_t pb = ((size_t)rowg*128 + cchunk)*2;   // [row][chunk] layout
        pstats[pb]   = m;
        pstats[pb+1] = s;
      }
    }
  }
}

// ---------------- per-row logsumexp: one wave per row, shfl merge --------------
__global__ void k_lsmfin(const float* __restrict__ ps, float* __restrict__ lg) {
  int gw = (blockIdx.x*256 + threadIdx.x)>>6;   // row
  int lane = threadIdx.x & 63;
  const float4 v = *(const float4*)&ps[(size_t)gw*256 + lane*4];  // {m0,s0,m1,s1}
  float M = fmaxf(v.x, v.z);
  float S = __expf(v.x-M)*v.y + __expf(v.z-M)*v.w;
  #pragma unroll
  for (int o=1;o<64;o<<=1){
    float M2 = __shfl_xor(M,o,64), S2 = __shfl_xor(S,o,64);
    float Mn = fmaxf(M,M2);
    S = S*__expf(M-Mn) + S2*__expf(M2-Mn);
    M = Mn;
  }
  if (lane==0) lg[gw] = M + logf(S);
}

// ---------------- final: out = (float)logit_f16 - lg[row] ----------------------
__global__ void k_lsub(const unsigned short* __restrict__ C16,
                       const float* __restrict__ lg, float* __restrict__ O) {
  int i = blockIdx.x*256 + threadIdx.x;   // over NN*8192/8 groups
  short8v v = ((const short8v*)C16)[i];
  f16x8 h = __builtin_bit_cast(f16x8, v);
  float L = lg[i>>10];                     // 1024 groups of 8 per row
  float4 o0, o1;
  o0.x=(float)h[0]-L; o0.y=(float)h[1]-L; o0.z=(float)h[2]-L; o0.w=(float)h[3]-L;
  o1.x=(float)h[4]-L; o1.y=(float)h[5]-L; o1.z=(float)h[6]-L; o1.w=(float)h[7]-L;
  ((float4*)O)[i*2]   = o0;
  ((float4*)O)[i*2+1] = o1;
}

extern "C" void kernel_launch(void* const* d_in, const int* in_sizes, int n_in,
                              void* d_out, int out_size, void* d_ws, size_t ws_size,
                              hipStream_t stream) {
  (void)in_sizes; (void)n_in; (void)out_size; (void)ws_size;
  const float* x0     = (const float*)d_in[0]; (void)x0;
  const int*   ei     = (const int*)d_in[1];
  const float* pseudo = (const float*)d_in[2];
  const float* W[6]; const float* R[6]; const float* Bb[6];
  for (int l=0;l<6;l++){
    W[l]=(const float*)d_in[3+3*l];
    R[l]=(const float*)d_in[4+3*l];
    Bb[l]=(const float*)d_in[5+3*l];
  }
  const float* L1w=(const float*)d_in[21];
  const float* L1b=(const float*)d_in[22];
  const float* L2w=(const float*)d_in[23];
  const float* L2b=(const float*)d_in[24];
  float* out = (float*)d_out;
  char* ws = (char*)d_ws;

  size_t off=0;
  auto alloc=[&](size_t bytes)->void*{
    size_t o=off; off += (bytes+511)&~511ULL; return (void*)(ws+o);
  };
  unsigned* bpk =(unsigned*)alloc((size_t)NE*8*4);
  int*   kidx  =(int*)  alloc((size_t)NE*8*4);
  int*   pcnt  =(int*)  alloc((size_t)NB2*4);
  int*   poff  =(int*)  alloc((size_t)(NB2+1)*4);
  int*   pcur  =(int*)  alloc((size_t)(NB2+1)*4);
  uint2* pairs =(uint2*)alloc((size_t)PAIRCAP*8);
  float* M1    =(float*)alloc((size_t)NN*128*4);
  unsigned short* Wh=(unsigned short*)alloc((size_t)NT*64*72*2);
  unsigned short* xpk32=(unsigned short*)alloc((size_t)NN*32*2);
  unsigned short* hpkA =(unsigned short*)alloc((size_t)NN*64*2);
  unsigned short* hpkB =(unsigned short*)alloc((size_t)NN*64*2);
  float* hf    =(float*)alloc((size_t)NN*64*4);
  unsigned short* A2=(unsigned short*)alloc((size_t)NN*K2*2);
  unsigned short* B2=(unsigned short*)alloc((size_t)NN*K2*2);
  unsigned short* C16=(unsigned short*)alloc((size_t)NN*NN*2);
  float* pstats=(float*)alloc((size_t)NN*128*2*4);
  float* lg    =(float*)alloc((size_t)NN*4);
  float* cpart = out;   // d_out (256 MB) doubles as split-K partial scratch

  const int* src = ei;
  const int* dst = ei + NE;

  hipMemsetAsync(pcnt, 0, (size_t)NB2*4, stream);
  hipMemsetAsync(pairs, 0, (size_t)PAIRCAP*8, stream);   // zero-pad buckets
  k_basis<<<NE/256,256,0,stream>>>(pseudo,dst,bpk,kidx,pcnt);
  k_pscan<<<1,1024,0,stream>>>(pcnt,poff,pcur);
  k_pplace<<<NE/256,256,0,stream>>>(src,dst,bpk,kidx,pcur,pairs);
  k_spplace<<<NN/256,256,0,stream>>>(poff,pairs);
  k_bprep<<<512,256,0,stream>>>(L2w,B2);

  dim3 gg(64, 8);
  dim3 gf(NRB, NSL);
  // layer 1: 1 -> 32 (x == 1): pair-built M1, GEMM, reduce (permuted f16 out)
  k_fbuild1<<<NRB,256,0,stream>>>(pairs,poff,M1);
  k_gconv<32><<<gg,256,0,stream>>>(M1,W[0],cpart,125,128,8);
  k_reduce1<<<(NN*32)/256,256,0,stream>>>(cpart,R[0],Bb[0],xpk32);
  // layer 2: 32 -> 64
  k_wprep<32><<<NT,256,0,stream>>>(W[1],R[1],Wh);
  k_mconv<32><<<gf,256,0,stream>>>(xpk32,Wh,pairs,poff,cpart);
  k_reduce2<<<(NN*64)/256,256,0,stream>>>(cpart,Bb[1],hpkA,hf);
  // layers 3..6: 64 -> 64
  unsigned short* hin=hpkA; unsigned short* hout=hpkB;
  for (int l=2;l<6;l++){
    k_wprep<64><<<NT,256,0,stream>>>(W[l],R[l],Wh);
    k_mconv<64><<<gf,256,0,stream>>>(hin,Wh,pairs,poff,cpart);
    k_reduce2<<<(NN*64)/256,256,0,stream>>>(cpart,Bb[l],hout,hf);
    unsigned short* tmp=hin; hin=hout; hout=tmp;
  }
  // hf holds layer-6 fp32 output
  k_l1<<<NN,256,0,stream>>>(hf,L1w,L1b,A2);
  dim3 g2(64,64);
  k_l2g<<<g2,256,0,stream>>>(A2,B2,L2b,C16,pstats);
  k_lsmfin<<<NN*64/256,256,0,stream>>>(pstats,lg);
  k_lsub<<<(NN*8192/8)/256,256,0,stream>>>(C16,lg,out);
}